// Round 13
// baseline (112.387 us; speedup 1.0000x reference)
//
#include <hip/hip_runtime.h>
#include <math.h>

#define BB 8
#define CC 64
#define HH 128
#define WW 128
#define EE 8
#define OO 64
#define HID 128
#define GATEC 96
#define NP 8     // patches per spatial dim
#define PP 16    // patch size

typedef __attribute__((ext_vector_type(8))) short bf16x8;
typedef __attribute__((ext_vector_type(4))) float f32x4;

static __device__ __forceinline__ unsigned short f2bf(float f) {
  unsigned int u = __builtin_bit_cast(unsigned int, f);
  unsigned int r = (u + 0x7FFFu + ((u >> 16) & 1u)) >> 16;   // RNE
  return (unsigned short)r;
}

// ---------------- Kernel A+P fused: router gates + weight pack ----------------
// blocks 0..511: gate (b*64 + pi*8 + pj); blocks 512..639: pack
// pack layout: per tap (=e*9+t), 8 chunks of 512 halfwords (1 KB), chunk
// i = ks*4+ot; within a chunk lane l=(kg*16+px) holds its 8 contiguous
// halfwords -> each A-fragment load is ONE fully-coalesced 1 KB load:
//   dst = tap*4096 + ((c>>5)*4 + (o>>4))*512 + (((c>>3)&3)*16 + (o&15))*8 + (c&7)
__global__ __launch_bounds__(256) void prep_kernel(
    const float* __restrict__ x,
    const float* __restrict__ W1, const float* __restrict__ b1,
    const float* __restrict__ W2, const float* __restrict__ b2,
    const float* __restrict__ We,
    float* __restrict__ probs, unsigned short* __restrict__ wp) {
  __shared__ float ps[256];
  __shared__ float g[GATEC];
  __shared__ float hbuf[HID];
  __shared__ float lg[EE];

  if (blockIdx.x >= 512) {
    int idx = (blockIdx.x - 512) * 256 + threadIdx.x;   // (e*64+o)*64+c
    if (idx < EE * OO * CC) {
      int c = idx & 63;
      int o = (idx >> 6) & 63;
      int e = idx >> 12;
      const float* src = We + (size_t)idx * 9;          // 9 contiguous taps
      float v[9];
#pragma unroll
      for (int t = 0; t < 9; ++t) v[t] = src[t];
      int base = (((c >> 5) * 4 + (o >> 4)) << 9)
               + ((((c >> 3) & 3) * 16 + (o & 15)) << 3) + (c & 7);
#pragma unroll
      for (int t = 0; t < 9; ++t) {
        int et = e * 9 + t;
        wp[(et << 12) + base] = f2bf(v[t]);
      }
    }
    return;
  }

  int blk = blockIdx.x;        // b*64 + pi*8 + pj
  int b  = blk >> 6;
  int pi = (blk >> 3) & 7;
  int pj = blk & 7;
  int t  = threadIdx.x;

  {
    int c = t >> 2, q = t & 3;
    const f32x4* xb = (const f32x4*)(x + ((size_t)(b * CC + c) * HH + pi * PP + q * 4) * WW + pj * PP);
    float s = 0.f;
    for (int r = 0; r < 4; ++r) {
#pragma unroll
      for (int v4 = 0; v4 < 4; ++v4) {
        f32x4 w = xb[r * (WW / 4) + v4];
        s += w[0] + w[1] + w[2] + w[3];
      }
    }
    ps[t] = s;
  }
  __syncthreads();
  if (t < CC) {
    g[t] = (ps[4*t] + ps[4*t+1] + ps[4*t+2] + ps[4*t+3]) * (1.f / 256.f);
  } else if (t < CC + 32) {
    int k = t - CC;
    int fi = k & 7, kind = k >> 3;
    float freq  = (float)(1 << fi);
    float coord = (kind < 2) ? ((pi + 0.5f) / 8.f) : ((pj + 0.5f) / 8.f);
    float a = 6.28318530717958647692f * freq * coord;
    g[t] = (kind & 1) ? cosf(a) : sinf(a);
  }
  __syncthreads();
  if (t < HID) {
    float acc = b1[t];
    const float* w = W1 + (size_t)t * GATEC;
    for (int c = 0; c < GATEC; ++c) acc += w[c] * g[c];
    hbuf[t] = fmaxf(acc, 0.f);
  }
  __syncthreads();
  if (t < EE) {
    float acc = b2[t];
    const float* w = W2 + (size_t)t * HID;
    for (int k = 0; k < HID; ++k) acc += w[k] * hbuf[k];
    lg[t] = acc;
  }
  __syncthreads();
  if (t < EE) {
    float m = lg[0];
    for (int e = 1; e < EE; ++e) m = fmaxf(m, lg[e]);
    float sum = 0.f;
    for (int e = 0; e < EE; ++e) sum += expf(lg[e] - m);
    probs[((size_t)(b * EE + t) * NP + pi) * NP + pj] = expf(lg[t] - m) / sum;
  }
}

// ---------------- Kernel B: MFMA expert conv + gated combine ----------------
// NEW vs R12: region 8 rows x 16 cols (one patch column), grid 1024; 4 waves;
// wave = 64 o x (2 rows x 16 cols) -> acc+outacc = 64 AGPR (was 128), so
// (256,3) cap=170 fits dual-bank prefetch -> 3 blocks/CU = 3 waves/SIMD
// (was 2). Same pipe ratios (4 bx reads / 16 MFMA per tap), weight stream
// L1-resident. Single gate per wave (wave spans exactly one patch).
__global__ __launch_bounds__(256, 3) void conv_moe(
    const float* __restrict__ x,
    const unsigned short* __restrict__ wp,   // packed [tap][8 x 1KB chunks] bf16
    const float* __restrict__ be,
    const float* __restrict__ probs, float* __restrict__ out) {
  int bx0 = blockIdx.x;            // rg*8 + cg
  int b   = blockIdx.y;
  int rg = bx0 >> 3, cg = bx0 & 7;
  const int h0 = rg * 8, w0 = cg * 16;
  const int pi = rg >> 1;          // patch row
  const int pj = cg;               // patch col (one per block)

  int lane = threadIdx.x & 63;
  int wave = threadIdx.x >> 6;     // 0..3
  int px   = lane & 15;
  int kg   = lane >> 4;            // 0..3

  __shared__ char xs[8 * 181 * 16];   // [j][sp=r*18+col (180 used, pad 181)][16B]

  // ---- stage x tile (once): 10 rows x 18 cols halo ----
  for (int i = 0; i < 6; ++i) {
    int idx = i * 256 + threadIdx.x;
    if (idx < 1440) {
      int j  = idx / 180;
      int sp = idx - j * 180;
      int r = sp / 18, col = sp - r * 18;
      int gr = h0 + r - 1, gc = w0 + col - 1;
      bf16x8 v;
      if (gr >= 0 && gr < HH && gc >= 0 && gc < WW) {
        const float* xb = x + ((size_t)(b * CC + j * 8) * HH + gr) * WW + gc;
#pragma unroll
        for (int q = 0; q < 8; ++q) v[q] = (short)f2bf(xb[(size_t)q * HH * WW]);
      } else {
#pragma unroll
        for (int q = 0; q < 8; ++q) v[q] = 0;
      }
      *(bf16x8*)(xs + (j * 181 + sp) * 16) = v;
    }
  }
  __syncthreads();   // ONLY barrier: xs read-only below

  // per-lane LDS base: chunk j = ks*4+kg, spatial (wave*2 rows, col px)
  const char* lb = xs + (kg * 181 + wave * 36 + px) * 16;
  // per-lane weight pointer: lane's 16B within each 1KB chunk
  const unsigned short* wq = wp + lane * 8;

  f32x4 outacc[4][2], acc[4][2];   // [ot][rowp]
#pragma unroll
  for (int ot = 0; ot < 4; ++ot)
#pragma unroll
    for (int rp = 0; rp < 2; ++rp) { outacc[ot][rp] = (f32x4)(0.f); acc[ot][rp] = (f32x4)(0.f); }

#define LOADW(bank, tap)                                                        \
  { _Pragma("unroll") for (int i_ = 0; i_ < 8; ++i_)                            \
      bank[i_] = *(const bf16x8*)(wq + (size_t)(tap) * 4096 + i_ * 512); }

  // ds addr = lb + off(tap, SGPR) + const[ks*724 + rowp*18]*16   (724 = 4*181)
#define TAP(BANK, off)                                                          \
  {                                                                             \
    const char* ta = lb + (off);                                                \
    bf16x8 bx_[2][2];                                                           \
    _Pragma("unroll")                                                           \
    for (int ks_ = 0; ks_ < 2; ++ks_)                                           \
      _Pragma("unroll")                                                         \
      for (int rp_ = 0; rp_ < 2; ++rp_)                                         \
        bx_[ks_][rp_] = *(const bf16x8*)(ta + (ks_ * 724 + rp_ * 18) * 16);     \
    __builtin_amdgcn_s_setprio(1);                                              \
    _Pragma("unroll")                                                           \
    for (int ks_ = 0; ks_ < 2; ++ks_)                                           \
      _Pragma("unroll")                                                         \
      for (int ot_ = 0; ot_ < 4; ++ot_)                                         \
        _Pragma("unroll")                                                       \
        for (int rp_ = 0; rp_ < 2; ++rp_)                                       \
          acc[ot_][rp_] = __builtin_amdgcn_mfma_f32_16x16x32_bf16(              \
              BANK[ks_ * 4 + ot_], bx_[ks_][rp_], acc[ot_][rp_], 0, 0, 0);      \
    __builtin_amdgcn_s_setprio(0);                                              \
  }

#define EPILOGUE(eidx)                                                          \
  {                                                                             \
    float gt = probs[((size_t)(b * EE + (eidx)) * NP + pi) * NP + pj];          \
    _Pragma("unroll")                                                           \
    for (int ot_ = 0; ot_ < 4; ++ot_) {                                         \
      f32x4 bias = *(const f32x4*)(be + (eidx) * OO + ot_ * 16 + kg * 4);       \
      _Pragma("unroll")                                                         \
      for (int rp_ = 0; rp_ < 2; ++rp_) {                                       \
        _Pragma("unroll")                                                       \
        for (int r_ = 0; r_ < 4; ++r_) {                                        \
          outacc[ot_][rp_][r_] += gt * fmaxf(acc[ot_][rp_][r_] + bias[r_], 0.f);\
          acc[ot_][rp_][r_] = 0.f;                                              \
        }                                                                       \
      }                                                                         \
    }                                                                           \
  }

  // off advance over taps (row-major 3x3): dx++ -> +16B; dy++ -> +(18-2)*16B
#define ADVANCE()                                                               \
  {                                                                             \
    if (t9 == 8) { EPILOGUE(e); ++e; t9 = 0; dx = 0; off = 0; }                 \
    else { ++t9; if (++dx == 3) { dx = 0; off += 256; } else { off += 16; } }   \
  }

  bf16x8 awA[8], awB[8];
  LOADW(awA, 0);
  LOADW(awB, 1);

  int e = 0, t9 = 0, dx = 0, off = 0;
#pragma unroll 1
  for (int u = 0; u < 36; ++u) {
    TAP(awA, off);
    if (u < 35) LOADW(awA, 2 * u + 2);
    ADVANCE();
    TAP(awB, off);
    if (u < 35) LOADW(awB, 2 * u + 3);
    ADVANCE();
  }

  // ---- store: lane holds o = ot*16+kg*4+r, col = w0 + px ----
#pragma unroll
  for (int ot = 0; ot < 4; ++ot) {
#pragma unroll
    for (int rp = 0; rp < 2; ++rp) {
      int o = ot * 16 + kg * 4;
      int h = h0 + wave * 2 + rp;
      float* op = out + ((size_t)(b * OO + o) * HH + h) * WW + w0 + px;
#pragma unroll
      for (int r = 0; r < 4; ++r)
        op[(size_t)r * HH * WW] = outacc[ot][rp][r];
    }
  }
#undef LOADW
#undef TAP
#undef EPILOGUE
#undef ADVANCE
}

extern "C" void kernel_launch(void* const* d_in, const int* in_sizes, int n_in,
                              void* d_out, int out_size, void* d_ws, size_t ws_size,
                              hipStream_t stream) {
  const float* x  = (const float*)d_in[0];
  const float* We = (const float*)d_in[1];
  const float* be = (const float*)d_in[2];
  const float* W1 = (const float*)d_in[3];
  const float* b1 = (const float*)d_in[4];
  const float* W2 = (const float*)d_in[5];
  const float* b2 = (const float*)d_in[6];
  float* out = (float*)d_out;

  float* probs = (float*)d_ws;                                  // 16 KB
  unsigned short* wpk = (unsigned short*)((char*)d_ws + 16384); // 576 KB packed weights

  prep_kernel<<<dim3(512 + (EE * OO * CC + 255) / 256), dim3(256), 0, stream>>>(
      x, W1, b1, W2, b2, We, probs, wpk);
  conv_moe<<<dim3(16 * 8, BB), dim3(256), 0, stream>>>(x, wpk, be, probs, out);
}